// Round 18
// baseline (24.131 us; speedup 1.0000x reference)
//
#include <hip/hip_runtime.h>

// ROI max-pool (aspect-preserving "OCR" variant) — separable two-phase, v15.
// feats: (B=4, C=128, H=64, W=512) fp32
// rois:  (N, 5) fp32 = [batch, x1, y1, x2, y2] image coords, spatial scale 0.25
// out:   (N, C, PH=8, PW=32) fp32
//
// R16 + phase-1 lane remap: lane = (channel t>>3, w-slot t&7). One load instr
// covers 8 channels x 32 cols at ~full lane packing (R16: 44% packed, 4
// instrs/row); now ceil(wwid/32) ~ 2 instrs/row average. Exact-NH template
// (nh wave-uniform <= 5) issues nh loads per slot-block back-to-back, then a
// max-tree and one float4 LDS write (ch-stride 116 floats = 20 banks mod 32,
// <=2-way, free). Phase 2 unchanged: 5-wide masked w-max from LDS.
// 32768 single-wave blocks.

#define PHB 8
#define PWB 32
#define CHB 8           // channels per block
#define WST 116         // staged width cap: ceil(32*bsw) <= 108, +3 align
#define BLK 64

static __device__ __forceinline__ float4 max4(float4 a, float4 b) {
    float4 r;
    r.x = fmaxf(a.x, b.x); r.y = fmaxf(a.y, b.y);
    r.z = fmaxf(a.z, b.z); r.w = fmaxf(a.w, b.w);
    return r;
}

template<int NH>
static __device__ __forceinline__ void stage_rows(
    const float* __restrict__ p,   // this lane's channel plane
    int Wc, int hs, int wlo_al, int wwid, int sl,
    float* __restrict__ dst)       // &smax[ch * WST]
{
#pragma unroll
    for (int si = 0; si < 4; ++si) {
        int col = (sl + si * 8) * 4;          // float offset in window
        if (col < wwid) {                     // per-lane mask (execz-skipped
            float4 v[NH];                     //  when whole wave inactive)
#pragma unroll
            for (int rr = 0; rr < NH; ++rr)
                v[rr] = *reinterpret_cast<const float4*>(
                    p + (hs + rr) * Wc + wlo_al + col);
            float4 rm = v[0];
#pragma unroll
            for (int rr = 1; rr < NH; ++rr) rm = max4(rm, v[rr]);
            *reinterpret_cast<float4*>(dst + col) = rm;
        }
    }
}

__global__ __launch_bounds__(BLK) void ocr_roi_pool_kernel(
    const float* __restrict__ feats,
    const float* __restrict__ rois,
    float* __restrict__ out,
    int Cc, int Hc, int Wc)
{
#pragma clang fp contract(off)
    __shared__ float smax[CHB * WST + 8];   // +8: phase-2 unroll over-read pad

    int b  = blockIdx.x;               // ((n*8 + ph)*16 + cg)
    int cg = b & 15;
    int ph = (b >> 4) & 7;
    int n  = b >> 7;
    int c0 = cg * CHB;

    // ---- ROI params: block-uniform -> scalar ----
    const float* r = rois + n * 5;
    int rb  = (int)r[0];
    int rsw = (int)floorf(r[1] * 0.25f + 0.5f);
    int rsh = (int)floorf(r[2] * 0.25f + 0.5f);
    int rew = (int)floorf(r[3] * 0.25f + 0.5f);
    int reh = (int)floorf(r[4] * 0.25f + 0.5f);

    int roi_w = max(rew - rsw + 1, 1);
    int roi_h = max(reh - rsh + 1, 1);
    int rpw   = (PHB * roi_w + roi_h - 1) / roi_h;

    float bsh = (float)roi_h / (float)PHB;
    float bsw = (float)roi_w / (float)rpw;

    // h-range for this ph (uniform over block), exact reference math
    int hs = (int)floorf((float)ph * bsh) + rsh;
    int he = (int)ceilf((float)(ph + 1) * bsh) + rsh;
    hs = min(max(hs, 0), Hc);
    he = min(max(he, 0), Hc);
    int nh = he - hs;                  // 0..5, wave-uniform

    // staged w-window: covers every NON-PAD bin's reads; 4-aligned base.
    int wlo = min(max(rsw, 0), Wc);
    int whi = (int)ceilf((float)PWB * bsw) + rsw;
    whi = min(whi, rew + 4);
    whi = min(max(whi, 0), Wc);
    int wlo_al = wlo & ~3;
    int wwid = min(whi - wlo_al, WST);

    int t      = threadIdx.x;
    int lane_w = t & 31;
    int cslot  = t >> 5;               // 0..1 (phase 2)
    int ch     = t >> 3;               // 0..7 (phase 1 channel)
    int sl     = t & 7;                // 0..7 (phase 1 w-slot)

    const int plane_stride = Hc * Wc;  // 32768

    // ---- Phase 1: rowmax -> LDS (packed (ch,slot) lanes, exact-nh) ----
    if (nh > 0) {
        const float* plane =
            feats + ((size_t)(rb * Cc + c0 + ch) * Hc) * Wc;
        float* dst = &smax[ch * WST];
        switch (nh) {
        case 1:  stage_rows<1>(plane, Wc, hs, wlo_al, wwid, sl, dst); break;
        case 2:  stage_rows<2>(plane, Wc, hs, wlo_al, wwid, sl, dst); break;
        case 3:  stage_rows<3>(plane, Wc, hs, wlo_al, wwid, sl, dst); break;
        case 4:  stage_rows<4>(plane, Wc, hs, wlo_al, wwid, sl, dst); break;
        default: stage_rows<5>(plane, Wc, hs, wlo_al, wwid, sl, dst); break;
        }
    }
    __syncthreads();

    // ---- Phase 2: colmax from LDS (fixed 5-wide masked unroll), store ----
    int pw = lane_w;
    int ws = (int)floorf((float)pw * bsw) + rsw;
    int we = (int)ceilf((float)(pw + 1) * bsw) + rsw;
    ws = min(max(ws, 0), Wc);
    we = min(max(we, 0), Wc);

    bool pad   = (ws >= rew);
    bool empty = (he <= hs) || (we <= ws);

    size_t obase = (((size_t)n * Cc + c0 + cslot) * PHB + ph) * PWB + pw;
    if (pad || empty) {
#pragma unroll
        for (int j = 0; j < 4; ++j)
            out[obase + (size_t)(2 * j) * (PHB * PWB)] = 0.0f;
    } else {
        int base = ws - wlo_al;        // >= 0
        int nw   = we - ws;            // 1..5 (bsw <= 3.375)
#pragma unroll
        for (int j = 0; j < 4; ++j) {
            const float* row = &smax[(cslot + 2 * j) * WST + base];
            float m = -1e37f;
#pragma unroll
            for (int i = 0; i < 5; ++i) {        // 5 independent ds_reads,
                float v = row[i];                // masked beyond nw
                m = (i < nw) ? fmaxf(m, v) : m;
            }
            out[obase + (size_t)(2 * j) * (PHB * PWB)] = m;
        }
    }
}

extern "C" void kernel_launch(void* const* d_in, const int* in_sizes, int n_in,
                              void* d_out, int out_size, void* d_ws, size_t ws_size,
                              hipStream_t stream) {
    const float* feats = (const float*)d_in[0];
    const float* rois  = (const float*)d_in[1];
    float* out = (float*)d_out;

    const int Cc = 128, Hc = 64, Wc = 512;
    int nroi = in_sizes[1] / 5;
    int blocks = nroi * PHB * (Cc / CHB);   // 32768

    ocr_roi_pool_kernel<<<blocks, BLK, 0, stream>>>(feats, rois, out, Cc, Hc, Wc);
}